// Round 1
// baseline (244.072 us; speedup 1.0000x reference)
//
#include <hip/hip_runtime.h>
#include <math.h>

#define BB 4
#define NN 16384
#define CC 384
#define NE 128
#define KK 64
#define CAP 1024

typedef unsigned short ushort_t;
typedef __attribute__((ext_vector_type(8))) short bf16x8;
typedef __attribute__((ext_vector_type(4))) float f32x4;
#define MFMA(a, b, c) __builtin_amdgcn_mfma_f32_16x16x32_bf16(a, b, c, 0, 0, 0)

// Monotone map: larger float -> larger u32
__device__ inline unsigned fkey(float f) {
    unsigned b = __float_as_uint(f);
    return (b & 0x80000000u) ? ~b : (b | 0x80000000u);
}
__device__ inline ushort_t bf16rne(float f) {
    unsigned u = __float_as_uint(f);
    unsigned r = u + 0x7FFFu + ((u >> 16) & 1u);
    return (ushort_t)(r >> 16);
}
__device__ inline float bf16tof(ushort_t h) {
    return __uint_as_float(((unsigned)h) << 16);
}
// Cheap near-RNE hi/lo split for a pair of floats (unbiased residual ~2^-17)
__device__ inline void cvt2(float fa, float fb, unsigned& hp, unsigned& lp) {
    unsigned ua = __float_as_uint(fa), ub = __float_as_uint(fb);
    unsigned ra = ua + 0x8000u, rb = ub + 0x8000u;
    hp = (ra >> 16) | (rb & 0xFFFF0000u);
    float ha = __uint_as_float(ra & 0xFFFF0000u);
    float hb = __uint_as_float(rb & 0xFFFF0000u);
    float la = fa - ha, lb = fb - hb;           // exact (Sterbenz)
    unsigned lra = __float_as_uint(la) + 0x8000u;
    unsigned lrb = __float_as_uint(lb) + 0x8000u;
    lp = (lra >> 16) | (lrb & 0xFFFF0000u);
}

// global -> LDS direct DMA, 16B per lane. LDS dest must be wave-uniform base
// (HW adds lane*16); global src is per-lane.
__device__ inline void load_lds16(const ushort_t* g, ushort_t* l) {
    __builtin_amdgcn_global_load_lds(
        (const __attribute__((address_space(1))) unsigned int*)(const void*)g,
        (__attribute__((address_space(3))) unsigned int*)(void*)l, 16, 0, 0);
}

// Parallel bin select over 4096-bin LDS histogram (1024 threads, 16 waves).
__device__ inline void bin_select4k(const unsigned* hist, int t, int* wsum,
                                    int* sh_bin, int* sh_r, int r) {
    int base = t * 4;
    int c0 = hist[base], c1 = hist[base + 1], c2 = hist[base + 2], c3 = hist[base + 3];
    int csum = c0 + c1 + c2 + c3;
    int lane = t & 63, wid = t >> 6;
    int x = csum;
#pragma unroll
    for (int off = 1; off < 64; off <<= 1) {
        int v = __shfl_down(x, off, 64);
        if (lane + off < 64) x += v;     // inclusive suffix within wave
    }
    if (lane == 0) wsum[wid] = x;
    __syncthreads();
    int after = 0;
    for (int w2 = wid + 1; w2 < 16; ++w2) after += wsum[w2];
    int S = x - csum + after;            // elems in bins strictly above base+3
    if (S < r && S + c3 >= r) { *sh_bin = base + 3; *sh_r = r - S; }
    S += c3;
    if (S < r && S + c2 >= r) { *sh_bin = base + 2; *sh_r = r - S; }
    S += c2;
    if (S < r && S + c1 >= r) { *sh_bin = base + 1; *sh_r = r - S; }
    S += c1;
    if (S < r && S + c0 >= r) { *sh_bin = base + 0; *sh_r = r - S; }
    __syncthreads();
}

// ---------------- K1: per-row sumsq + class-token dot -> u32 ranking key ----------------
__global__ __launch_bounds__(256) void k_scores(const float* __restrict__ nf,
                                                const float* __restrict__ ct,
                                                unsigned* __restrict__ keys,
                                                float* __restrict__ invn) {
    int wave = threadIdx.x >> 6;
    int lane = threadIdx.x & 63;
    int row  = blockIdx.x * 4 + wave;
    const float* x = nf + (size_t)row * CC;
    float4 a  = ((const float4*)x)[lane];
    float2 c2 = ((const float2*)(x + 256))[lane];
    float4 ta = ((const float4*)ct)[lane];
    float2 tc = ((const float2*)(ct + 256))[lane];
    float ss = a.x*a.x + a.y*a.y + a.z*a.z + a.w*a.w + c2.x*c2.x + c2.y*c2.y;
    float dt = ta.x*a.x + ta.y*a.y + ta.z*a.z + ta.w*a.w + tc.x*c2.x + tc.y*c2.y;
#pragma unroll
    for (int off = 32; off; off >>= 1) {
        ss += __shfl_xor(ss, off, 64);
        dt += __shfl_xor(dt, off, 64);
    }
    if (lane == 0) {
        float inv = 1.0f / fmaxf(sqrtf(ss), 1e-12f);
        invn[row] = inv;
        keys[row] = fkey(dt * inv);
    }
}

// ---------------- K2: top-128 per batch + meta + fused center gather/split ----------------
__global__ __launch_bounds__(1024) void k_top128(const unsigned* __restrict__ keys,
                                                 const float* __restrict__ nf,
                                                 const float* __restrict__ invn,
                                                 float* __restrict__ meta,
                                                 ushort_t* __restrict__ Ahi,
                                                 ushort_t* __restrict__ Alo) {
    __shared__ unsigned hist[4096];
    __shared__ int wsum[16];
    __shared__ int sh_bin, sh_r;
    __shared__ unsigned cu[NE];
    __shared__ int cil[NE];
    __shared__ unsigned eqk[CAP];
    __shared__ int eqi[CAP];
    __shared__ int cnt_gt, cnt_eq;
    __shared__ int ocid[NE];
    int b = blockIdx.x;
    int t = threadIdx.x;
    const uint4* rowv = (const uint4*)(keys + b * NN);
    if (t == 0) { cnt_gt = 0; cnt_eq = 0; }
    ((uint4*)hist)[t] = make_uint4(0, 0, 0, 0);
    __syncthreads();
    uint4 u0 = rowv[t], u1 = rowv[t + 1024], u2 = rowv[t + 2048], u3 = rowv[t + 3072];
    atomicAdd(&hist[u0.x >> 20], 1u); atomicAdd(&hist[u0.y >> 20], 1u);
    atomicAdd(&hist[u0.z >> 20], 1u); atomicAdd(&hist[u0.w >> 20], 1u);
    atomicAdd(&hist[u1.x >> 20], 1u); atomicAdd(&hist[u1.y >> 20], 1u);
    atomicAdd(&hist[u1.z >> 20], 1u); atomicAdd(&hist[u1.w >> 20], 1u);
    atomicAdd(&hist[u2.x >> 20], 1u); atomicAdd(&hist[u2.y >> 20], 1u);
    atomicAdd(&hist[u2.z >> 20], 1u); atomicAdd(&hist[u2.w >> 20], 1u);
    atomicAdd(&hist[u3.x >> 20], 1u); atomicAdd(&hist[u3.y >> 20], 1u);
    atomicAdd(&hist[u3.z >> 20], 1u); atomicAdd(&hist[u3.w >> 20], 1u);
    __syncthreads();
    bin_select4k(hist, t, wsum, &sh_bin, &sh_r, NE);
    unsigned bin = (unsigned)sh_bin;
    int r = sh_r;
#define EMIT128(uu, nn) { unsigned tb = (uu) >> 20; \
    if (tb > bin) { int p = atomicAdd(&cnt_gt, 1); cu[p] = (uu); cil[p] = (nn); } \
    else if (tb == bin) { int p = atomicAdd(&cnt_eq, 1); if (p < CAP) { eqk[p] = (uu); eqi[p] = (nn); } } }
    EMIT128(u0.x, 4*t+0); EMIT128(u0.y, 4*t+1); EMIT128(u0.z, 4*t+2); EMIT128(u0.w, 4*t+3);
    EMIT128(u1.x, 4096+4*t+0); EMIT128(u1.y, 4096+4*t+1); EMIT128(u1.z, 4096+4*t+2); EMIT128(u1.w, 4096+4*t+3);
    EMIT128(u2.x, 8192+4*t+0); EMIT128(u2.y, 8192+4*t+1); EMIT128(u2.z, 8192+4*t+2); EMIT128(u2.w, 8192+4*t+3);
    EMIT128(u3.x, 12288+4*t+0); EMIT128(u3.y, 12288+4*t+1); EMIT128(u3.z, 12288+4*t+2); EMIT128(u3.w, 12288+4*t+3);
#undef EMIT128
    __syncthreads();
    int ne = cnt_eq < CAP ? cnt_eq : CAP;
    for (int i = t; i < ne; i += 1024) {
        unsigned ki = eqk[i]; int ii = eqi[i], rk = 0;
        for (int j = 0; j < ne; ++j) {
            unsigned kj = eqk[j];
            rk += (kj > ki) || (kj == ki && eqi[j] < ii);
        }
        if (rk < r) { cu[cnt_gt + rk] = ki; cil[cnt_gt + rk] = ii; }
    }
    __syncthreads();
    if (t < NE) {
        unsigned mu = cu[t]; int mi = cil[t], rk = 0;
#pragma unroll 4
        for (int j = 0; j < NE; ++j) {
            unsigned ou = cu[j]; int oi = cil[j];
            rk += (ou > mu) || (ou == mu && oi < mi);
        }
        ocid[rk] = mi;
    }
    __syncthreads();
    if (t < NE) {
        int ci = ocid[t];
        float zc = (float)(ci >> 10) * 2.0f;
        float yc = (float)((ci >> 5) & 31);
        float xc = (float)(ci & 31);
        float mz = fmaxf(zc * zc, (30.f - zc) * (30.f - zc));
        float my = fmaxf(yc * yc, (31.f - yc) * (31.f - yc));
        float mx = fmaxf(xc * xc, (31.f - xc) * (31.f - xc));
        float md = sqrtf(mz + my + mx);
        int be = b * NE + t;
        meta[be * 4 + 0] = zc;
        meta[be * 4 + 1] = yc;
        meta[be * 4 + 2] = xc;
        meta[be * 4 + 3] = 1.0f / (md + 1e-8f);
    }
    // ---- fused center gather -> exact-RNE bf16 hi/lo split (was k_centers) ----
    {
        int wid2 = t >> 6, lane2 = t & 63;
        for (int e = wid2; e < NE; e += 16) {
            int ci = ocid[e];
            float inv = invn[b * NN + ci];
            const float* src = nf + ((size_t)b * NN + ci) * CC;
            float4 a  = ((const float4*)src)[lane2];
            float2 cv = ((const float2*)(src + 256))[lane2];
            a.x *= inv; a.y *= inv; a.z *= inv; a.w *= inv;
            cv.x *= inv; cv.y *= inv;
            ushort4 h4; ushort2 h2;
            h4.x = bf16rne(a.x); h4.y = bf16rne(a.y); h4.z = bf16rne(a.z); h4.w = bf16rne(a.w);
            h2.x = bf16rne(cv.x); h2.y = bf16rne(cv.y);
            ushort4 l4; ushort2 l2;
            l4.x = bf16rne(a.x - bf16tof(h4.x)); l4.y = bf16rne(a.y - bf16tof(h4.y));
            l4.z = bf16rne(a.z - bf16tof(h4.z)); l4.w = bf16rne(a.w - bf16tof(h4.w));
            l2.x = bf16rne(cv.x - bf16tof(h2.x)); l2.y = bf16rne(cv.y - bf16tof(h2.y));
            ushort_t* dh = Ahi + ((size_t)b * NE + e) * CC;
            ushort_t* dl = Alo + ((size_t)b * NE + e) * CC;
            ((ushort4*)dh)[lane2] = h4;
            ((ushort2*)(dh + 256))[lane2] = h2;
            ((ushort4*)dl)[lane2] = l4;
            ((ushort2*)(dl + 256))[lane2] = l2;
        }
    }
}

// ---------------- K3: bf16-split MFMA GEMM, 128 edges x 64 nodes/block ----------------
// acc = Ahi*Bhi + Ahi*Blo + Alo*Bhi (fp32 accum). Each B element is read+converted
// exactly once across the grid. A staged via global_load_lds width-16 (linear LDS).
// LDS ~27 KB -> 4 blocks/CU.
__global__ __launch_bounds__(256, 4) void k_gemm(const float* __restrict__ nf,
                                                 const ushort_t* __restrict__ Ahi,
                                                 const ushort_t* __restrict__ Alo,
                                                 const float* __restrict__ invn,
                                                 const float* __restrict__ meta,
                                                 const float* __restrict__ temp,
                                                 unsigned* __restrict__ outk) {
    __shared__ ushort_t Ah[4 * 128 * 8], Al[4 * 128 * 8];   // linear [k8][e][8], DMA dest
    __shared__ ushort_t Bh[4][66][8], Bl[4][66][8];         // [k8][n 64+pad][8]
    __shared__ float ms[NE * 4];
    __shared__ float invs_s[64];
    int b  = blockIdx.y;
    int n0 = blockIdx.x * 64;
    int t  = threadIdx.x;
    int w = t >> 6, lane = t & 63, quad = lane >> 4, mrow = lane & 15;
    for (int i = t; i < NE * 4; i += 256) ms[i] = meta[b * NE * 4 + i];
    if (t < 64) invs_s[t] = invn[b * NN + n0 + t];
    f32x4 acc[2][4];
#pragma unroll
    for (int i = 0; i < 2; ++i)
#pragma unroll
        for (int j = 0; j < 4; ++j) acc[i][j] = (f32x4)0.f;
    const ushort_t* Abh = Ahi + (size_t)b * NE * CC;
    const ushort_t* Abl = Alo + (size_t)b * NE * CC;
    // A DMA mapping: slot s = k8*128 + e holds elems (e, kt + k8*8 .. +8).
    // Wave w issues chunks q64 = 2w, 2w+1; lane covers slot = q64*64 + lane.
    int q64a = w * 2, q64b = w * 2 + 1;
    int slota = q64a * 64 + lane, slotb = q64b * 64 + lane;
    const ushort_t* gha = Abh + (size_t)(slota & 127) * CC + (slota >> 7) * 8;
    const ushort_t* ghb = Abh + (size_t)(slotb & 127) * CC + (slotb >> 7) * 8;
    const ushort_t* gla = Abl + (size_t)(slota & 127) * CC + (slota >> 7) * 8;
    const ushort_t* glb = Abl + (size_t)(slotb & 127) * CC + (slotb >> 7) * 8;
    ushort_t* ldsAha = &Ah[(q64a * 64) * 8];
    ushort_t* ldsAhb = &Ah[(q64b * 64) * 8];
    ushort_t* ldsAla = &Al[(q64a * 64) * 8];
    ushort_t* ldsAlb = &Al[(q64b * 64) * 8];
    // B: one (n, k8) group of 8 floats per thread per K-step
    int bn = t >> 2, bk8 = t & 3;
    const float* bs = nf + ((size_t)b * NN + n0 + bn) * CC + bk8 * 8;
    float4 pBa = ((const float4*)bs)[0];
    float4 pBb = ((const float4*)bs)[1];
    for (int kt = 0; kt < CC; kt += 32) {
        __syncthreads();
        // A: async DMA for this K-chunk (overlaps B convert below)
        load_lds16(gha + kt, ldsAha);
        load_lds16(ghb + kt, ldsAhb);
        load_lds16(gla + kt, ldsAla);
        load_lds16(glb + kt, ldsAlb);
        // B: convert prefetched regs -> hi/lo bf16, store
        {
            uint4 ph, pl;
            cvt2(pBa.x, pBa.y, ph.x, pl.x);
            cvt2(pBa.z, pBa.w, ph.y, pl.y);
            cvt2(pBb.x, pBb.y, ph.z, pl.z);
            cvt2(pBb.z, pBb.w, ph.w, pl.w);
            *(uint4*)&Bh[bk8][bn][0] = ph;
            *(uint4*)&Bl[bk8][bn][0] = pl;
        }
        if (kt + 32 < CC) {                  // register prefetch of next B chunk
            pBa = ((const float4*)(bs + kt + 32))[0];
            pBb = ((const float4*)(bs + kt + 32))[1];
        }
        __syncthreads();                     // drains vmcnt (DMA) + lgkm (ds_write)
        bf16x8 afh[2], afl[2], bfh[4], bfl[4];
#pragma unroll
        for (int i = 0; i < 2; ++i) {
            int m = w * 32 + i * 16 + mrow;
            afh[i] = *(const bf16x8*)&Ah[(quad * 128 + m) * 8];
            afl[i] = *(const bf16x8*)&Al[(quad * 128 + m) * 8];
        }
#pragma unroll
        for (int j = 0; j < 4; ++j) {
            int n = j * 16 + mrow;
            bfh[j] = *(const bf16x8*)&Bh[quad][n][0];
            bfl[j] = *(const bf16x8*)&Bl[quad][n][0];
        }
#pragma unroll
        for (int i = 0; i < 2; ++i)
#pragma unroll
            for (int j = 0; j < 4; ++j) {
                acc[i][j] = MFMA(afh[i], bfh[j], acc[i][j]);
                acc[i][j] = MFMA(afh[i], bfl[j], acc[i][j]);
                acc[i][j] = MFMA(afl[i], bfh[j], acc[i][j]);
            }
    }
    float scale = 0.9f / temp[0];
#pragma unroll
    for (int j = 0; j < 4; ++j) {
        int nloc = j * 16 + mrow;
        int n = n0 + nloc;
        float invnn = invs_s[nloc];
        float zf = (float)(n >> 10) * 2.0f;
        float yf = (float)((n >> 5) & 31);
        float xf = (float)(n & 31);
#pragma unroll
        for (int i = 0; i < 2; ++i) {
#pragma unroll
            for (int r = 0; r < 4; ++r) {
                int el = w * 32 + i * 16 + quad * 4 + r;
                float zc = ms[el * 4 + 0], yc = ms[el * 4 + 1], xc = ms[el * 4 + 2], ivd = ms[el * 4 + 3];
                float dz = zf - zc, dy = yf - yc, dx = xf - xc;
                float dist = sqrtf(dz * dz + dy * dy + dx * dx);
                float v = scale * invnn * acc[i][j][r] + 0.1f * (1.0f - dist * ivd);
                outk[((size_t)(b * NE + el)) * NN + n] = fkey(v);
            }
        }
    }
}

// ---------------- K4: top-64 per hyperedge -> 16384-bit incidence bitmap ----------------
// 512 threads (8 waves): cheaper barriers, 3 blocks/CU.
__global__ __launch_bounds__(512) void k_top64(const unsigned* __restrict__ comb,
                                               unsigned* __restrict__ bmg) {
    __shared__ unsigned hist[4096];
    __shared__ unsigned bm[512];
    __shared__ int wsum[8];
    __shared__ int sh_bin, sh_r;
    __shared__ unsigned eqk[CAP];
    __shared__ int eqi[CAP];
    __shared__ int cnt_eq;
    int be = blockIdx.x;
    int t  = threadIdx.x;
    const uint4* rowv = (const uint4*)(comb + (size_t)be * NN);
    if (t == 0) cnt_eq = 0;
    ((uint4*)hist)[t] = make_uint4(0, 0, 0, 0);
    ((uint4*)hist)[t + 512] = make_uint4(0, 0, 0, 0);
    if (t < 128) ((uint4*)bm)[t] = make_uint4(0, 0, 0, 0);
    __syncthreads();
    uint4 u[8];
#pragma unroll
    for (int i = 0; i < 8; ++i) u[i] = rowv[t + 512 * i];
#pragma unroll
    for (int i = 0; i < 8; ++i) {
        atomicAdd(&hist[u[i].x >> 20], 1u); atomicAdd(&hist[u[i].y >> 20], 1u);
        atomicAdd(&hist[u[i].z >> 20], 1u); atomicAdd(&hist[u[i].w >> 20], 1u);
    }
    __syncthreads();
    // bin select: 8 bins per thread, 8-wave suffix scan
    {
        int base = t * 8;
        int c[8]; int csum = 0;
#pragma unroll
        for (int i = 0; i < 8; ++i) { c[i] = hist[base + i]; csum += c[i]; }
        int lane = t & 63, wid = t >> 6;
        int x = csum;
#pragma unroll
        for (int off = 1; off < 64; off <<= 1) {
            int v = __shfl_down(x, off, 64);
            if (lane + off < 64) x += v;
        }
        if (lane == 0) wsum[wid] = x;
        __syncthreads();
        int after = 0;
        for (int w2 = wid + 1; w2 < 8; ++w2) after += wsum[w2];
        int S = x - csum + after;        // elems strictly above this thread's bins
#pragma unroll
        for (int i = 7; i >= 0; --i) {
            if (S < KK && S + c[i] >= KK) { sh_bin = base + i; sh_r = KK - S; }
            S += c[i];
        }
        __syncthreads();
    }
    unsigned bin = (unsigned)sh_bin;
    int r = sh_r;
#define EMIT64(uu, nn) { unsigned tb = (uu) >> 20; \
    if (tb > bin) { atomicOr(&bm[(nn) >> 5], 1u << ((nn) & 31)); } \
    else if (tb == bin) { int p = atomicAdd(&cnt_eq, 1); if (p < CAP) { eqk[p] = (uu); eqi[p] = (nn); } } }
#pragma unroll
    for (int i = 0; i < 8; ++i) {
        int nb = 4 * (t + 512 * i);
        EMIT64(u[i].x, nb + 0); EMIT64(u[i].y, nb + 1);
        EMIT64(u[i].z, nb + 2); EMIT64(u[i].w, nb + 3);
    }
#undef EMIT64
    __syncthreads();
    int ne = cnt_eq < CAP ? cnt_eq : CAP;
    for (int i = t; i < ne; i += 512) {
        unsigned ki = eqk[i]; int ii = eqi[i], rk = 0;
        for (int j = 0; j < ne; ++j) {
            unsigned kj = eqk[j];
            rk += (kj > ki) || (kj == ki && eqi[j] < ii);
        }
        if (rk < r) atomicOr(&bm[ii >> 5], 1u << (ii & 31));
    }
    __syncthreads();
    if (t < 128) ((uint4*)(bmg + (size_t)be * 512))[t] = ((uint4*)bm)[t];
}

// ---------------- K5: expand bitmaps -> H (B, N, Ne), fully coalesced ----------------
__global__ __launch_bounds__(256) void k_expand(const unsigned* __restrict__ bmg,
                                                float* __restrict__ H) {
    __shared__ unsigned wl[256];     // 2 words per edge (covers 64 n)
    int b  = blockIdx.y;
    int n0 = blockIdx.x * 64;
    int t  = threadIdx.x;
    int w0 = n0 >> 5;
    wl[t] = bmg[((size_t)b * NE + (t >> 1)) * 512 + w0 + (t & 1)];
    __syncthreads();
    float4* dst = (float4*)(H + ((size_t)b * NN + n0) * NE);
#pragma unroll
    for (int i = 0; i < 8; ++i) {
        int flat = t + 256 * i;          // [0, 2048): n-local*32 + f4
        int nl = flat >> 5, f4 = flat & 31;
        int wsel = nl >> 5, bit = nl & 31;
        int e = f4 * 4;
        float4 v;
        v.x = (float)((wl[(e + 0) * 2 + wsel] >> bit) & 1u);
        v.y = (float)((wl[(e + 1) * 2 + wsel] >> bit) & 1u);
        v.z = (float)((wl[(e + 2) * 2 + wsel] >> bit) & 1u);
        v.w = (float)((wl[(e + 3) * 2 + wsel] >> bit) & 1u);
        dst[flat] = v;
    }
}

extern "C" void kernel_launch(void* const* d_in, const int* in_sizes, int n_in,
                              void* d_out, int out_size, void* d_ws, size_t ws_size,
                              hipStream_t stream) {
    const float* nf   = (const float*)d_in[0];
    const float* ct   = (const float*)d_in[1];
    const float* temp = (const float*)d_in[2];
    float* out = (float*)d_out;                  // (B,N,Ne) f32 — also (B,Ne,N) u32-key scratch

    unsigned* keys = (unsigned*)d_ws;                      // B*N u32
    float* invn    = (float*)(keys + BB * NN);             // B*N f32
    float* meta    = invn + BB * NN;                       // B*NE*4 f32
    ushort_t* Ahi  = (ushort_t*)(meta + BB * NE * 4);      // B*NE*C bf16
    ushort_t* Alo  = Ahi + (size_t)BB * NE * CC;           // B*NE*C bf16
    unsigned* bmg  = (unsigned*)(Alo + (size_t)BB * NE * CC); // B*NE*512 u32 bitmap

    k_scores <<<BB * NN / 4, 256, 0, stream>>>(nf, ct, keys, invn);
    k_top128 <<<BB, 1024, 0, stream>>>(keys, nf, invn, meta, Ahi, Alo);
    k_gemm   <<<dim3(NN / 64, BB), 256, 0, stream>>>(nf, Ahi, Alo, invn, meta, temp, (unsigned*)out);
    k_top64  <<<BB * NE, 512, 0, stream>>>((const unsigned*)out, bmg);
    k_expand <<<dim3(NN / 64, BB), 256, 0, stream>>>(bmg, out);
}

// Round 2
// 233.961 us; speedup vs baseline: 1.0432x; 1.0432x over previous
//
#include <hip/hip_runtime.h>
#include <math.h>

#define BB 4
#define NN 16384
#define CC 384
#define NE 128
#define KK 64
#define CAP 1024

typedef unsigned short ushort_t;
typedef __attribute__((ext_vector_type(8))) short bf16x8;
typedef __attribute__((ext_vector_type(4))) float f32x4;
#define MFMA(a, b, c) __builtin_amdgcn_mfma_f32_16x16x32_bf16(a, b, c, 0, 0, 0)

// Monotone map: larger float -> larger u32
__device__ inline unsigned fkey(float f) {
    unsigned b = __float_as_uint(f);
    return (b & 0x80000000u) ? ~b : (b | 0x80000000u);
}
__device__ inline ushort_t bf16rne(float f) {
    unsigned u = __float_as_uint(f);
    unsigned r = u + 0x7FFFu + ((u >> 16) & 1u);
    return (ushort_t)(r >> 16);
}
__device__ inline float bf16tof(ushort_t h) {
    return __uint_as_float(((unsigned)h) << 16);
}
// Cheap near-RNE hi/lo split for a pair of floats (unbiased residual ~2^-17)
__device__ inline void cvt2(float fa, float fb, unsigned& hp, unsigned& lp) {
    unsigned ua = __float_as_uint(fa), ub = __float_as_uint(fb);
    unsigned ra = ua + 0x8000u, rb = ub + 0x8000u;
    hp = (ra >> 16) | (rb & 0xFFFF0000u);
    float ha = __uint_as_float(ra & 0xFFFF0000u);
    float hb = __uint_as_float(rb & 0xFFFF0000u);
    float la = fa - ha, lb = fb - hb;           // exact (Sterbenz)
    unsigned lra = __float_as_uint(la) + 0x8000u;
    unsigned lrb = __float_as_uint(lb) + 0x8000u;
    lp = (lra >> 16) | (lrb & 0xFFFF0000u);
}

// global -> LDS direct DMA, 16B per lane. LDS dest must be wave-uniform base
// (HW adds lane*16); global src is per-lane.
__device__ inline void load_lds16(const ushort_t* g, ushort_t* l) {
    __builtin_amdgcn_global_load_lds(
        (const __attribute__((address_space(1))) unsigned int*)(const void*)g,
        (__attribute__((address_space(3))) unsigned int*)(void*)l, 16, 0, 0);
}

// Parallel bin select over 4096-bin LDS histogram (1024 threads, 16 waves).
__device__ inline void bin_select4k(const unsigned* hist, int t, int* wsum,
                                    int* sh_bin, int* sh_r, int r) {
    int base = t * 4;
    int c0 = hist[base], c1 = hist[base + 1], c2 = hist[base + 2], c3 = hist[base + 3];
    int csum = c0 + c1 + c2 + c3;
    int lane = t & 63, wid = t >> 6;
    int x = csum;
#pragma unroll
    for (int off = 1; off < 64; off <<= 1) {
        int v = __shfl_down(x, off, 64);
        if (lane + off < 64) x += v;     // inclusive suffix within wave
    }
    if (lane == 0) wsum[wid] = x;
    __syncthreads();
    int after = 0;
    for (int w2 = wid + 1; w2 < 16; ++w2) after += wsum[w2];
    int S = x - csum + after;            // elems in bins strictly above base+3
    if (S < r && S + c3 >= r) { *sh_bin = base + 3; *sh_r = r - S; }
    S += c3;
    if (S < r && S + c2 >= r) { *sh_bin = base + 2; *sh_r = r - S; }
    S += c2;
    if (S < r && S + c1 >= r) { *sh_bin = base + 1; *sh_r = r - S; }
    S += c1;
    if (S < r && S + c0 >= r) { *sh_bin = base + 0; *sh_r = r - S; }
    __syncthreads();
}

// ---------------- K1: per-row sumsq + class-token dot -> u32 ranking key ----------------
__global__ __launch_bounds__(256) void k_scores(const float* __restrict__ nf,
                                                const float* __restrict__ ct,
                                                unsigned* __restrict__ keys,
                                                float* __restrict__ invn) {
    int wave = threadIdx.x >> 6;
    int lane = threadIdx.x & 63;
    int row  = blockIdx.x * 4 + wave;
    const float* x = nf + (size_t)row * CC;
    float4 a  = ((const float4*)x)[lane];
    float2 c2 = ((const float2*)(x + 256))[lane];
    float4 ta = ((const float4*)ct)[lane];
    float2 tc = ((const float2*)(ct + 256))[lane];
    float ss = a.x*a.x + a.y*a.y + a.z*a.z + a.w*a.w + c2.x*c2.x + c2.y*c2.y;
    float dt = ta.x*a.x + ta.y*a.y + ta.z*a.z + ta.w*a.w + tc.x*c2.x + tc.y*c2.y;
#pragma unroll
    for (int off = 32; off; off >>= 1) {
        ss += __shfl_xor(ss, off, 64);
        dt += __shfl_xor(dt, off, 64);
    }
    if (lane == 0) {
        float inv = 1.0f / fmaxf(sqrtf(ss), 1e-12f);
        invn[row] = inv;
        keys[row] = fkey(dt * inv);
    }
}

// ---------------- K2: top-128 per batch + meta + fused center gather/split ----------------
__global__ __launch_bounds__(1024) void k_top128(const unsigned* __restrict__ keys,
                                                 const float* __restrict__ nf,
                                                 const float* __restrict__ invn,
                                                 float* __restrict__ meta,
                                                 ushort_t* __restrict__ Ahi,
                                                 ushort_t* __restrict__ Alo) {
    __shared__ unsigned hist[4096];
    __shared__ int wsum[16];
    __shared__ int sh_bin, sh_r;
    __shared__ unsigned cu[NE];
    __shared__ int cil[NE];
    __shared__ unsigned eqk[CAP];
    __shared__ int eqi[CAP];
    __shared__ int cnt_gt, cnt_eq;
    __shared__ int ocid[NE];
    int b = blockIdx.x;
    int t = threadIdx.x;
    const uint4* rowv = (const uint4*)(keys + b * NN);
    if (t == 0) { cnt_gt = 0; cnt_eq = 0; }
    ((uint4*)hist)[t] = make_uint4(0, 0, 0, 0);
    __syncthreads();
    uint4 u0 = rowv[t], u1 = rowv[t + 1024], u2 = rowv[t + 2048], u3 = rowv[t + 3072];
    atomicAdd(&hist[u0.x >> 20], 1u); atomicAdd(&hist[u0.y >> 20], 1u);
    atomicAdd(&hist[u0.z >> 20], 1u); atomicAdd(&hist[u0.w >> 20], 1u);
    atomicAdd(&hist[u1.x >> 20], 1u); atomicAdd(&hist[u1.y >> 20], 1u);
    atomicAdd(&hist[u1.z >> 20], 1u); atomicAdd(&hist[u1.w >> 20], 1u);
    atomicAdd(&hist[u2.x >> 20], 1u); atomicAdd(&hist[u2.y >> 20], 1u);
    atomicAdd(&hist[u2.z >> 20], 1u); atomicAdd(&hist[u2.w >> 20], 1u);
    atomicAdd(&hist[u3.x >> 20], 1u); atomicAdd(&hist[u3.y >> 20], 1u);
    atomicAdd(&hist[u3.w >> 20], 1u); atomicAdd(&hist[u3.z >> 20], 1u);
    __syncthreads();
    bin_select4k(hist, t, wsum, &sh_bin, &sh_r, NE);
    unsigned bin = (unsigned)sh_bin;
    int r = sh_r;
#define EMIT128(uu, nn) { unsigned tb = (uu) >> 20; \
    if (tb > bin) { int p = atomicAdd(&cnt_gt, 1); cu[p] = (uu); cil[p] = (nn); } \
    else if (tb == bin) { int p = atomicAdd(&cnt_eq, 1); if (p < CAP) { eqk[p] = (uu); eqi[p] = (nn); } } }
    EMIT128(u0.x, 4*t+0); EMIT128(u0.y, 4*t+1); EMIT128(u0.z, 4*t+2); EMIT128(u0.w, 4*t+3);
    EMIT128(u1.x, 4096+4*t+0); EMIT128(u1.y, 4096+4*t+1); EMIT128(u1.z, 4096+4*t+2); EMIT128(u1.w, 4096+4*t+3);
    EMIT128(u2.x, 8192+4*t+0); EMIT128(u2.y, 8192+4*t+1); EMIT128(u2.z, 8192+4*t+2); EMIT128(u2.w, 8192+4*t+3);
    EMIT128(u3.x, 12288+4*t+0); EMIT128(u3.y, 12288+4*t+1); EMIT128(u3.z, 12288+4*t+2); EMIT128(u3.w, 12288+4*t+3);
#undef EMIT128
    __syncthreads();
    int ne = cnt_eq < CAP ? cnt_eq : CAP;
    for (int i = t; i < ne; i += 1024) {
        unsigned ki = eqk[i]; int ii = eqi[i], rk = 0;
        for (int j = 0; j < ne; ++j) {
            unsigned kj = eqk[j];
            rk += (kj > ki) || (kj == ki && eqi[j] < ii);
        }
        if (rk < r) { cu[cnt_gt + rk] = ki; cil[cnt_gt + rk] = ii; }
    }
    __syncthreads();
    if (t < NE) {
        unsigned mu = cu[t]; int mi = cil[t], rk = 0;
#pragma unroll 4
        for (int j = 0; j < NE; ++j) {
            unsigned ou = cu[j]; int oi = cil[j];
            rk += (ou > mu) || (ou == mu && oi < mi);
        }
        ocid[rk] = mi;
    }
    __syncthreads();
    if (t < NE) {
        int ci = ocid[t];
        float zc = (float)(ci >> 10) * 2.0f;
        float yc = (float)((ci >> 5) & 31);
        float xc = (float)(ci & 31);
        float mz = fmaxf(zc * zc, (30.f - zc) * (30.f - zc));
        float my = fmaxf(yc * yc, (31.f - yc) * (31.f - yc));
        float mx = fmaxf(xc * xc, (31.f - xc) * (31.f - xc));
        float md = sqrtf(mz + my + mx);
        int be = b * NE + t;
        meta[be * 4 + 0] = zc;
        meta[be * 4 + 1] = yc;
        meta[be * 4 + 2] = xc;
        meta[be * 4 + 3] = 1.0f / (md + 1e-8f);
    }
    // ---- fused center gather -> exact-RNE bf16 hi/lo split (was k_centers) ----
    {
        int wid2 = t >> 6, lane2 = t & 63;
        for (int e = wid2; e < NE; e += 16) {
            int ci = ocid[e];
            float inv = invn[b * NN + ci];
            const float* src = nf + ((size_t)b * NN + ci) * CC;
            float4 a  = ((const float4*)src)[lane2];
            float2 cv = ((const float2*)(src + 256))[lane2];
            a.x *= inv; a.y *= inv; a.z *= inv; a.w *= inv;
            cv.x *= inv; cv.y *= inv;
            ushort4 h4; ushort2 h2;
            h4.x = bf16rne(a.x); h4.y = bf16rne(a.y); h4.z = bf16rne(a.z); h4.w = bf16rne(a.w);
            h2.x = bf16rne(cv.x); h2.y = bf16rne(cv.y);
            ushort4 l4; ushort2 l2;
            l4.x = bf16rne(a.x - bf16tof(h4.x)); l4.y = bf16rne(a.y - bf16tof(h4.y));
            l4.z = bf16rne(a.z - bf16tof(h4.z)); l4.w = bf16rne(a.w - bf16tof(h4.w));
            l2.x = bf16rne(cv.x - bf16tof(h2.x)); l2.y = bf16rne(cv.y - bf16tof(h2.y));
            ushort_t* dh = Ahi + ((size_t)b * NE + e) * CC;
            ushort_t* dl = Alo + ((size_t)b * NE + e) * CC;
            ((ushort4*)dh)[lane2] = h4;
            ((ushort2*)(dh + 256))[lane2] = h2;
            ((ushort4*)dl)[lane2] = l4;
            ((ushort2*)(dl + 256))[lane2] = l2;
        }
    }
}

// ---------------- K3: bf16-split MFMA GEMM, 128 edges x 128 nodes/block ----------------
// 2x2 wave grid (halves LDS read redundancy), double-buffered LDS, A via
// global_load_lds DMA, single raw barrier per K-step with counted vmcnt(4)
// (A-DMAs drained, B fp32 prefetch left in flight). LDS 66.5 KB -> 2 blocks/CU.
__global__ __launch_bounds__(256, 2) void k_gemm(const float* __restrict__ nf,
                                                 const ushort_t* __restrict__ Ahi,
                                                 const ushort_t* __restrict__ Alo,
                                                 const float* __restrict__ invn,
                                                 const float* __restrict__ meta,
                                                 const float* __restrict__ temp,
                                                 unsigned* __restrict__ outk) {
    __shared__ ushort_t Ah[2][4096], Al[2][4096];   // [buf][slot*8], slot = k8*128 + e
    __shared__ ushort_t Bh[2][4096], Bl[2][4096];   // [buf][slot*8], slot = k8*128 + n
    __shared__ float ms[NE * 4];
    __shared__ float invs_s[128];
    int b  = blockIdx.y;
    int n0 = blockIdx.x * 128;
    int t  = threadIdx.x;
    int w = t >> 6, lane = t & 63, quad = lane >> 4, mrow = lane & 15;
    int wr = w >> 1, wc = w & 1;                 // 2x2 wave grid
    for (int i = t; i < NE * 4; i += 256) ms[i] = meta[b * NE * 4 + i];
    if (t < 128) invs_s[t] = invn[b * NN + n0 + t];
    f32x4 acc[4][4];
#pragma unroll
    for (int i = 0; i < 4; ++i)
#pragma unroll
        for (int j = 0; j < 4; ++j) acc[i][j] = (f32x4)0.f;
    const ushort_t* Abh = Ahi + (size_t)b * NE * CC;
    const ushort_t* Abl = Alo + (size_t)b * NE * CC;
    // A DMA: wave w covers slots [128w, 128w+128) = k8 = w, e = {lane, 64+lane}
    const ushort_t* gh0 = Abh + (size_t)lane * CC + w * 8;
    const ushort_t* gh1 = Abh + (size_t)(64 + lane) * CC + w * 8;
    const ushort_t* gl0 = Abl + (size_t)lane * CC + w * 8;
    const ushort_t* gl1 = Abl + (size_t)(64 + lane) * CC + w * 8;
    int adst0 = 1024 * w, adst1 = 1024 * w + 512;    // chunk LDS bases (ushort units)
    // B staging: thread t handles slots sb0 = (t&3)*128 + (t>>2), sb1 = sb0 + 64
    int sb0 = (t & 3) * 128 + (t >> 2);
    int sb1 = sb0 + 64;
    const float* bs0 = nf + ((size_t)b * NN + n0 + (t >> 2)) * CC + (t & 3) * 8;
    const float* bs1 = bs0 + (size_t)64 * CC;
    // ---- prologue: stage kstep 0 into buf 0, prefetch B(32) ----
    float4 p0a = ((const float4*)bs0)[0], p0b = ((const float4*)bs0)[1];
    float4 p1a = ((const float4*)bs1)[0], p1b = ((const float4*)bs1)[1];
    load_lds16(gh0, &Ah[0][adst0]);
    load_lds16(gh1, &Ah[0][adst1]);
    load_lds16(gl0, &Al[0][adst0]);
    load_lds16(gl1, &Al[0][adst1]);
    __builtin_amdgcn_sched_barrier(0);
    {
        uint4 ph, pl;
        cvt2(p0a.x, p0a.y, ph.x, pl.x); cvt2(p0a.z, p0a.w, ph.y, pl.y);
        cvt2(p0b.x, p0b.y, ph.z, pl.z); cvt2(p0b.z, p0b.w, ph.w, pl.w);
        *(uint4*)&Bh[0][sb0 * 8] = ph; *(uint4*)&Bl[0][sb0 * 8] = pl;
        cvt2(p1a.x, p1a.y, ph.x, pl.x); cvt2(p1a.z, p1a.w, ph.y, pl.y);
        cvt2(p1b.x, p1b.y, ph.z, pl.z); cvt2(p1b.z, p1b.w, ph.w, pl.w);
        *(uint4*)&Bh[0][sb1 * 8] = ph; *(uint4*)&Bl[0][sb1 * 8] = pl;
    }
    p0a = ((const float4*)(bs0 + 32))[0]; p0b = ((const float4*)(bs0 + 32))[1];
    p1a = ((const float4*)(bs1 + 32))[0]; p1b = ((const float4*)(bs1 + 32))[1];
    asm volatile("s_waitcnt vmcnt(4) lgkmcnt(0)" ::: "memory");
    __builtin_amdgcn_s_barrier();
    __builtin_amdgcn_sched_barrier(0);
    int cur = 0;
    for (int ks = 0; ks < 12; ++ks) {
        int nxt = cur ^ 1;
        if (ks < 11) {
            int kt = (ks + 1) * 32;
            load_lds16(gh0 + kt, &Ah[nxt][adst0]);
            load_lds16(gh1 + kt, &Ah[nxt][adst1]);
            load_lds16(gl0 + kt, &Al[nxt][adst0]);
            load_lds16(gl1 + kt, &Al[nxt][adst1]);
            __builtin_amdgcn_sched_barrier(0);
            uint4 ph, pl;
            cvt2(p0a.x, p0a.y, ph.x, pl.x); cvt2(p0a.z, p0a.w, ph.y, pl.y);
            cvt2(p0b.x, p0b.y, ph.z, pl.z); cvt2(p0b.z, p0b.w, ph.w, pl.w);
            *(uint4*)&Bh[nxt][sb0 * 8] = ph; *(uint4*)&Bl[nxt][sb0 * 8] = pl;
            cvt2(p1a.x, p1a.y, ph.x, pl.x); cvt2(p1a.z, p1a.w, ph.y, pl.y);
            cvt2(p1b.x, p1b.y, ph.z, pl.z); cvt2(p1b.z, p1b.w, ph.w, pl.w);
            *(uint4*)&Bh[nxt][sb1 * 8] = ph; *(uint4*)&Bl[nxt][sb1 * 8] = pl;
            int kt2 = (ks + 2 < 12) ? (ks + 2) * 32 : 0;   // dummy reload at tail
            p0a = ((const float4*)(bs0 + kt2))[0]; p0b = ((const float4*)(bs0 + kt2))[1];
            p1a = ((const float4*)(bs1 + kt2))[0]; p1b = ((const float4*)(bs1 + kt2))[1];
        }
        bf16x8 afh[4], afl[4], bfh[4], bfl[4];
#pragma unroll
        for (int i = 0; i < 4; ++i) {
            int m = wr * 64 + i * 16 + mrow;
            afh[i] = *(const bf16x8*)&Ah[cur][(quad * 128 + m) * 8];
            afl[i] = *(const bf16x8*)&Al[cur][(quad * 128 + m) * 8];
        }
#pragma unroll
        for (int j = 0; j < 4; ++j) {
            int n = wc * 64 + j * 16 + mrow;
            bfh[j] = *(const bf16x8*)&Bh[cur][(quad * 128 + n) * 8];
            bfl[j] = *(const bf16x8*)&Bl[cur][(quad * 128 + n) * 8];
        }
#pragma unroll
        for (int i = 0; i < 4; ++i)
#pragma unroll
            for (int j = 0; j < 4; ++j) {
                acc[i][j] = MFMA(afh[i], bfh[j], acc[i][j]);
                acc[i][j] = MFMA(afh[i], bfl[j], acc[i][j]);
                acc[i][j] = MFMA(afl[i], bfh[j], acc[i][j]);
            }
        if (ks < 11) {
            asm volatile("s_waitcnt vmcnt(4) lgkmcnt(0)" ::: "memory");
            __builtin_amdgcn_s_barrier();
            __builtin_amdgcn_sched_barrier(0);
        }
        cur = nxt;
    }
    float scale = 0.9f / temp[0];
#pragma unroll
    for (int j = 0; j < 4; ++j) {
        int nloc = wc * 64 + j * 16 + mrow;
        int n = n0 + nloc;
        float invnn = invs_s[nloc];
        float zf = (float)(n >> 10) * 2.0f;
        float yf = (float)((n >> 5) & 31);
        float xf = (float)(n & 31);
#pragma unroll
        for (int i = 0; i < 4; ++i) {
#pragma unroll
            for (int r = 0; r < 4; ++r) {
                int el = wr * 64 + i * 16 + quad * 4 + r;
                float zc = ms[el * 4 + 0], yc = ms[el * 4 + 1], xc = ms[el * 4 + 2], ivd = ms[el * 4 + 3];
                float dz = zf - zc, dy = yf - yc, dx = xf - xc;
                float dist = sqrtf(dz * dz + dy * dy + dx * dx);
                float v = scale * invnn * acc[i][j][r] + 0.1f * (1.0f - dist * ivd);
                outk[((size_t)(b * NE + el)) * NN + n] = fkey(v);
            }
        }
    }
}

// ---------------- K4: top-64 per hyperedge -> 16384-bit incidence bitmap ----------------
// 512 threads (8 waves): cheaper barriers, 3 blocks/CU.
__global__ __launch_bounds__(512) void k_top64(const unsigned* __restrict__ comb,
                                               unsigned* __restrict__ bmg) {
    __shared__ unsigned hist[4096];
    __shared__ unsigned bm[512];
    __shared__ int wsum[8];
    __shared__ int sh_bin, sh_r;
    __shared__ unsigned eqk[CAP];
    __shared__ int eqi[CAP];
    __shared__ int cnt_eq;
    int be = blockIdx.x;
    int t  = threadIdx.x;
    const uint4* rowv = (const uint4*)(comb + (size_t)be * NN);
    if (t == 0) cnt_eq = 0;
    ((uint4*)hist)[t] = make_uint4(0, 0, 0, 0);
    ((uint4*)hist)[t + 512] = make_uint4(0, 0, 0, 0);
    if (t < 128) ((uint4*)bm)[t] = make_uint4(0, 0, 0, 0);
    __syncthreads();
    uint4 u[8];
#pragma unroll
    for (int i = 0; i < 8; ++i) u[i] = rowv[t + 512 * i];
#pragma unroll
    for (int i = 0; i < 8; ++i) {
        atomicAdd(&hist[u[i].x >> 20], 1u); atomicAdd(&hist[u[i].y >> 20], 1u);
        atomicAdd(&hist[u[i].z >> 20], 1u); atomicAdd(&hist[u[i].w >> 20], 1u);
    }
    __syncthreads();
    // bin select: 8 bins per thread, 8-wave suffix scan
    {
        int base = t * 8;
        int c[8]; int csum = 0;
#pragma unroll
        for (int i = 0; i < 8; ++i) { c[i] = hist[base + i]; csum += c[i]; }
        int lane = t & 63, wid = t >> 6;
        int x = csum;
#pragma unroll
        for (int off = 1; off < 64; off <<= 1) {
            int v = __shfl_down(x, off, 64);
            if (lane + off < 64) x += v;
        }
        if (lane == 0) wsum[wid] = x;
        __syncthreads();
        int after = 0;
        for (int w2 = wid + 1; w2 < 8; ++w2) after += wsum[w2];
        int S = x - csum + after;        // elems strictly above this thread's bins
#pragma unroll
        for (int i = 7; i >= 0; --i) {
            if (S < KK && S + c[i] >= KK) { sh_bin = base + i; sh_r = KK - S; }
            S += c[i];
        }
        __syncthreads();
    }
    unsigned bin = (unsigned)sh_bin;
    int r = sh_r;
#define EMIT64(uu, nn) { unsigned tb = (uu) >> 20; \
    if (tb > bin) { atomicOr(&bm[(nn) >> 5], 1u << ((nn) & 31)); } \
    else if (tb == bin) { int p = atomicAdd(&cnt_eq, 1); if (p < CAP) { eqk[p] = (uu); eqi[p] = (nn); } } }
#pragma unroll
    for (int i = 0; i < 8; ++i) {
        int nb = 4 * (t + 512 * i);
        EMIT64(u[i].x, nb + 0); EMIT64(u[i].y, nb + 1);
        EMIT64(u[i].z, nb + 2); EMIT64(u[i].w, nb + 3);
    }
#undef EMIT64
    __syncthreads();
    int ne = cnt_eq < CAP ? cnt_eq : CAP;
    for (int i = t; i < ne; i += 512) {
        unsigned ki = eqk[i]; int ii = eqi[i], rk = 0;
        for (int j = 0; j < ne; ++j) {
            unsigned kj = eqk[j];
            rk += (kj > ki) || (kj == ki && eqi[j] < ii);
        }
        if (rk < r) atomicOr(&bm[ii >> 5], 1u << (ii & 31));
    }
    __syncthreads();
    if (t < 128) ((uint4*)(bmg + (size_t)be * 512))[t] = ((uint4*)bm)[t];
}

// ---------------- K5: expand bitmaps -> H (B, N, Ne), fully coalesced ----------------
__global__ __launch_bounds__(256) void k_expand(const unsigned* __restrict__ bmg,
                                                float* __restrict__ H) {
    __shared__ unsigned wl[256];     // 2 words per edge (covers 64 n)
    int b  = blockIdx.y;
    int n0 = blockIdx.x * 64;
    int t  = threadIdx.x;
    int w0 = n0 >> 5;
    wl[t] = bmg[((size_t)b * NE + (t >> 1)) * 512 + w0 + (t & 1)];
    __syncthreads();
    float4* dst = (float4*)(H + ((size_t)b * NN + n0) * NE);
#pragma unroll
    for (int i = 0; i < 8; ++i) {
        int flat = t + 256 * i;          // [0, 2048): n-local*32 + f4
        int nl = flat >> 5, f4 = flat & 31;
        int wsel = nl >> 5, bit = nl & 31;
        int e = f4 * 4;
        float4 v;
        v.x = (float)((wl[(e + 0) * 2 + wsel] >> bit) & 1u);
        v.y = (float)((wl[(e + 1) * 2 + wsel] >> bit) & 1u);
        v.z = (float)((wl[(e + 2) * 2 + wsel] >> bit) & 1u);
        v.w = (float)((wl[(e + 3) * 2 + wsel] >> bit) & 1u);
        dst[flat] = v;
    }
}

extern "C" void kernel_launch(void* const* d_in, const int* in_sizes, int n_in,
                              void* d_out, int out_size, void* d_ws, size_t ws_size,
                              hipStream_t stream) {
    const float* nf   = (const float*)d_in[0];
    const float* ct   = (const float*)d_in[1];
    const float* temp = (const float*)d_in[2];
    float* out = (float*)d_out;                  // (B,N,Ne) f32 — also (B,Ne,N) u32-key scratch

    unsigned* keys = (unsigned*)d_ws;                      // B*N u32
    float* invn    = (float*)(keys + BB * NN);             // B*N f32
    float* meta    = invn + BB * NN;                       // B*NE*4 f32
    ushort_t* Ahi  = (ushort_t*)(meta + BB * NE * 4);      // B*NE*C bf16
    ushort_t* Alo  = Ahi + (size_t)BB * NE * CC;           // B*NE*C bf16
    unsigned* bmg  = (unsigned*)(Alo + (size_t)BB * NE * CC); // B*NE*512 u32 bitmap

    k_scores <<<BB * NN / 4, 256, 0, stream>>>(nf, ct, keys, invn);
    k_top128 <<<BB, 1024, 0, stream>>>(keys, nf, invn, meta, Ahi, Alo);
    k_gemm   <<<dim3(NN / 128, BB), 256, 0, stream>>>(nf, Ahi, Alo, invn, meta, temp, (unsigned*)out);
    k_top64  <<<BB * NE, 512, 0, stream>>>((const unsigned*)out, bmg);
    k_expand <<<dim3(NN / 64, BB), 256, 0, stream>>>(bmg, out);
}